// Round 1
// baseline (203.360 us; speedup 1.0000x reference)
//
#include <hip/hip_runtime.h>
#include <hip/hip_bf16.h>
#include <math.h>

#define N_NODES 100000
#define N_EDGES 1000000
#define DIM 64
#define SCAN_BLOCKS 391   // ceil(N_NODES/256)
#define AGPAD 72          // LDS row stride in shorts (16-B aligned, conflict-light)
#define NCOPY 8           // XCD-privatized histogram copies

// Device dtypes (established empirically R1-R8): fp32 floats, int32 indices,
// fp32 output.
typedef __hip_bfloat16 bf16;
typedef __attribute__((ext_vector_type(8))) short short8;
typedef __attribute__((ext_vector_type(4))) float floatx4;

__device__ __forceinline__ float b2f(bf16 v) { return __bfloat162float(v); }

__device__ __forceinline__ unsigned int packbf2(float a, float b) {
    bf16 x = __float2bfloat16(a), y = __float2bfloat16(b);
    unsigned short ux = *(unsigned short*)&x, uy = *(unsigned short*)&y;
    return (unsigned int)ux | ((unsigned int)uy << 16);
}

__device__ __forceinline__ short f2bs(float v) {
    bf16 x = __float2bfloat16(v);
    return *(short*)&x;
}

__device__ __forceinline__ float2 upk(unsigned int u) {
    unsigned short lo = (unsigned short)(u & 0xffff);
    unsigned short hi = (unsigned short)(u >> 16);
    bf16 a = *(bf16*)&lo, b = *(bf16*)&hi;
    return make_float2(b2f(a), b2f(b));
}

__device__ __forceinline__ int clampN(int v) {
    return v < 0 ? 0 : (v >= N_NODES ? N_NODES - 1 : v);
}

// ---------------------------------------------------------------------------
// Fused pre-pass, disjoint block ranges:
//   blocks [0,977)      : degree histogram into XCD-private copy (b&7) +
//                         per-edge local-rank capture (pos)
//   blocks [977,7227)   : x fp32 -> xb bf16 rows (1.6M float4s exactly)
//   block  7227         : wt[d][k] = bf16 [Wl0 | Wr0] row-concat
// R10 theory: the shared-degi version serialized ~160 atomics per 64B line
// with cross-XCD line migration (~800cy each) = 53us. 8 private copies cut
// same-line count to ~20 and (round-robin dispatch) keep each copy XCD-local.
// ---------------------------------------------------------------------------
__global__ void hist_convert_kernel(const int* __restrict__ ei,
                                    int* __restrict__ degi8,
                                    int* __restrict__ pos,
                                    const float4* __restrict__ x4,
                                    uint2* __restrict__ xb4,
                                    const float* __restrict__ Wl0,
                                    const float* __restrict__ Wr0,
                                    short* __restrict__ wt) {
    int b = blockIdx.x;
    if (b < 977) {
        int idx = b * 256 + threadIdx.x;
        if (idx < N_EDGES / 4) {
            int* dg = degi8 + (b & (NCOPY - 1)) * N_NODES;
            int4 d4 = ((const int4*)(ei + N_EDGES))[idx];
            int4 p;
            p.x = atomicAdd(&dg[clampN(d4.x)], 1);
            p.y = atomicAdd(&dg[clampN(d4.y)], 1);
            p.z = atomicAdd(&dg[clampN(d4.z)], 1);
            p.w = atomicAdd(&dg[clampN(d4.w)], 1);
            ((int4*)pos)[idx] = p;
        }
    } else if (b < 7227) {
        int idx = (b - 977) * 256 + threadIdx.x;   // < 1,600,000 exactly
        float4 f = x4[idx];
        xb4[idx] = make_uint2(packbf2(f.x, f.y), packbf2(f.z, f.w));
    } else {
        for (int i = threadIdx.x; i < 8192; i += 256) {
            int d = i >> 7, k = i & 127;
            float v = (k < 64) ? Wl0[d * 64 + k] : Wr0[d * 64 + (k - 64)];
            wt[i] = f2bs(v);
        }
    }
}

// scan1 now also folds the 8 privatized histogram copies: per node, compute
// the exclusive prefix across copies (written back in place as per-copy rank
// bases for fill) and the total degree (written to degi for agg/final).
__global__ void scan1_kernel(int* __restrict__ degi8,
                             int* __restrict__ degi,
                             int* __restrict__ rowstart, int* __restrict__ bsum) {
    __shared__ int sc[256];
    int t = threadIdx.x;
    int i = blockIdx.x * 256 + t;
    int v = 0;
    if (i < N_NODES) {
        int sum = 0;
        #pragma unroll
        for (int c = 0; c < NCOPY; ++c) {
            int u = degi8[c * N_NODES + i];
            degi8[c * N_NODES + i] = sum;   // exclusive base for copy c
            sum += u;
        }
        degi[i] = sum;                      // total degree
        v = sum;
    }
    sc[t] = v;
    __syncthreads();
    #pragma unroll
    for (int off = 1; off < 256; off <<= 1) {
        int u = (t >= off) ? sc[t - off] : 0;
        __syncthreads();
        sc[t] += u;
        __syncthreads();
    }
    if (i < N_NODES) rowstart[i] = sc[t] - v;   // exclusive within block
    if (t == 255) bsum[blockIdx.x] = sc[t];
}

__global__ void scan2_kernel(int* __restrict__ bsum) {
    __shared__ int sc[512];
    int t = threadIdx.x;
    int v = (t < SCAN_BLOCKS) ? bsum[t] : 0;
    sc[t] = v;
    __syncthreads();
    #pragma unroll
    for (int off = 1; off < 512; off <<= 1) {
        int u = (t >= off) ? sc[t - off] : 0;
        __syncthreads();
        sc[t] += u;
        __syncthreads();
    }
    if (t < SCAN_BLOCKS) bsum[t] = sc[t] - v;   // exclusive
}

// fill: pure scatter, no atomics. pos carries each edge's rank within its
// hist block's private copy c = (idx>>8)&7; degi8[c][d] holds that copy's
// exclusive base after scan1.
__global__ void fill_kernel(const int* __restrict__ ei,
                            const int* __restrict__ rowstart,
                            const int* __restrict__ bsum,
                            const int* __restrict__ degi8,
                            const int* __restrict__ pos,
                            int* __restrict__ csr) {
    int idx = blockIdx.x * blockDim.x + threadIdx.x;
    if (idx < N_EDGES / 4) {
        const int* dg = degi8 + ((idx >> 8) & (NCOPY - 1)) * N_NODES;
        int4 s4 = ((const int4*)ei)[idx];
        int4 d4 = ((const int4*)(ei + N_EDGES))[idx];
        int4 p4 = ((const int4*)pos)[idx];
        int d;
        d = clampN(d4.x); csr[rowstart[d] + bsum[d >> 8] + dg[d] + p4.x] = clampN(s4.x);
        d = clampN(d4.y); csr[rowstart[d] + bsum[d >> 8] + dg[d] + p4.y] = clampN(s4.y);
        d = clampN(d4.z); csr[rowstart[d] + bsum[d >> 8] + dg[d] + p4.z] = clampN(s4.z);
        d = clampN(d4.w); csr[rowstart[d] + bsum[d >> 8] + dg[d] + p4.w] = clampN(s4.w);
    }
}

// ---------------------------------------------------------------------------
// Fused aggregate + GEMM + heads. Block = 256 threads = 16 nodes.
// Phase 1: 16-lane quarter-wave per node; lane owns 4 dims (uint2 = 4 bf16),
//   4 independent accumulators over the node's edge list (4 gathers in
//   flight), no cross-lane reduce; bf16 mean -> LDS As[16][AGPAD].
// Phase 2: wave w computes output dims d = w*16 + (lane&15) via 4x
//   mfma_f32_16x16x32_bf16 over K=128 = [mean | x]:
//   A-frag A[m=lane&15][k=quad*8+j] (mean from LDS, x from xb global);
//   B-frag = wt[d][k] rows; C/D: node = quad*4+reg, d = lane&15 (R9-verified).
//   Epilogue: relu, dual head dots, 16-lane shfl reduce over d, LDS-atomic
//   combine across the 4 waves. mu buffer eliminated entirely.
// ---------------------------------------------------------------------------
__global__ __launch_bounds__(256) void agg_gemm_kernel(
        const uint2* __restrict__ xb2, const short* __restrict__ xb,
        const short* __restrict__ wt,
        const int* __restrict__ rowstart, const int* __restrict__ bsum,
        const int* __restrict__ degi, const int* __restrict__ csr,
        const float* __restrict__ bl0, const float* __restrict__ Wl1,
        const float* __restrict__ Wr1,
        float* __restrict__ s, float* __restrict__ t) {
    __shared__ short As[16 * AGPAD];
    __shared__ float sRed[16], tRed[16];
    const int tid = threadIdx.x;
    const int nb = blockIdx.x * 16;          // 100000 = 6250*16, always full

    if (tid < 16) { sRed[tid] = 0.0f; tRed[tid] = 0.0f; }

    // ---- phase 1: aggregate ----
    {
        int qn = tid >> 4;     // node-local 0..15
        int l  = tid & 15;     // lane in quarter: dims 4l..4l+3
        int n = nb + qn;
        int beg = rowstart[n] + bsum[n >> 8];
        int cnt = degi[n];
        float4 A0 = make_float4(0.f, 0.f, 0.f, 0.f);
        float4 A1 = A0, A2 = A0, A3 = A0;
        int i = 0;
        for (; i + 4 <= cnt; i += 4) {
            int e0 = csr[beg + i],     e1 = csr[beg + i + 1];
            int e2 = csr[beg + i + 2], e3 = csr[beg + i + 3];
            uint2 u0 = xb2[(long)e0 * 16 + l];
            uint2 u1 = xb2[(long)e1 * 16 + l];
            uint2 u2 = xb2[(long)e2 * 16 + l];
            uint2 u3 = xb2[(long)e3 * 16 + l];
            float2 f; 
            f = upk(u0.x); A0.x += f.x; A0.y += f.y; f = upk(u0.y); A0.z += f.x; A0.w += f.y;
            f = upk(u1.x); A1.x += f.x; A1.y += f.y; f = upk(u1.y); A1.z += f.x; A1.w += f.y;
            f = upk(u2.x); A2.x += f.x; A2.y += f.y; f = upk(u2.y); A2.z += f.x; A2.w += f.y;
            f = upk(u3.x); A3.x += f.x; A3.y += f.y; f = upk(u3.y); A3.z += f.x; A3.w += f.y;
        }
        if (i < cnt) {
            uint2 u = xb2[(long)csr[beg + i] * 16 + l];
            float2 f = upk(u.x); A0.x += f.x; A0.y += f.y;
            f = upk(u.y); A0.z += f.x; A0.w += f.y;
        }
        if (i + 1 < cnt) {
            uint2 u = xb2[(long)csr[beg + i + 1] * 16 + l];
            float2 f = upk(u.x); A1.x += f.x; A1.y += f.y;
            f = upk(u.y); A1.z += f.x; A1.w += f.y;
        }
        if (i + 2 < cnt) {
            uint2 u = xb2[(long)csr[beg + i + 2] * 16 + l];
            float2 f = upk(u.x); A2.x += f.x; A2.y += f.y;
            f = upk(u.y); A2.z += f.x; A2.w += f.y;
        }
        float inv = 1.0f / fmaxf((float)cnt, 1.0f);
        float ax = (A0.x + A1.x + A2.x + A3.x) * inv;
        float ay = (A0.y + A1.y + A2.y + A3.y) * inv;
        float az = (A0.z + A1.z + A2.z + A3.z) * inv;
        float aw = (A0.w + A1.w + A2.w + A3.w) * inv;
        *(uint2*)&As[qn * AGPAD + 4 * l] =
            make_uint2(packbf2(ax, ay), packbf2(az, aw));
    }
    __syncthreads();

    // ---- phase 2: MFMA + heads ----
    const int lane = tid & 63;
    const int w = tid >> 6;
    const int r = lane & 15;
    const int quad = lane >> 4;

    short8 a0 = *(const short8*)&As[r * AGPAD + quad * 8];        // k  0..31
    short8 a1 = *(const short8*)&As[r * AGPAD + 32 + quad * 8];   // k 32..63
    const long xrow = (long)(nb + r) * 64 + quad * 8;
    short8 a2 = *(const short8*)(xb + xrow);                      // k 64..95
    short8 a3 = *(const short8*)(xb + xrow + 32);                 // k 96..127

    const int d = w * 16 + r;
    const short* brow = wt + (long)d * 128 + quad * 8;
    short8 b0 = *(const short8*)(brow);
    short8 b1 = *(const short8*)(brow + 32);
    short8 b2 = *(const short8*)(brow + 64);
    short8 b3 = *(const short8*)(brow + 96);

    float bb = bl0[d];
    floatx4 acc = {bb, bb, bb, bb};
    acc = __builtin_amdgcn_mfma_f32_16x16x32_bf16(a0, b0, acc, 0, 0, 0);
    acc = __builtin_amdgcn_mfma_f32_16x16x32_bf16(a1, b1, acc, 0, 0, 0);
    acc = __builtin_amdgcn_mfma_f32_16x16x32_bf16(a2, b2, acc, 0, 0, 0);
    acc = __builtin_amdgcn_mfma_f32_16x16x32_bf16(a3, b3, acc, 0, 0, 0);

    float w1 = Wl1[d], w2 = Wr1[d];
    float hs[4], ht[4];
    #pragma unroll
    for (int g = 0; g < 4; ++g) {
        float h = fmaxf(acc[g], 0.0f);
        hs[g] = h * w1;
        ht[g] = h * w2;
    }
    #pragma unroll
    for (int g = 0; g < 4; ++g) {
        #pragma unroll
        for (int off = 1; off < 16; off <<= 1) {
            hs[g] += __shfl_xor(hs[g], off, 64);
            ht[g] += __shfl_xor(ht[g], off, 64);
        }
    }
    if (r == 0) {
        #pragma unroll
        for (int g = 0; g < 4; ++g) {
            atomicAdd(&sRed[quad * 4 + g], hs[g]);
            atomicAdd(&tRed[quad * 4 + g], ht[g]);
        }
    }
    __syncthreads();
    if (tid < 16) {
        s[nb + tid] = sRed[tid];
        t[nb + tid] = tRed[tid];
    }
}

// ---------------------------------------------------------------------------
// Final: CSR-gather of s (4-wide ILP), mean, + bl1 + t, sigmoid, fp32 out.
// ---------------------------------------------------------------------------
__global__ void final_kernel(const float* __restrict__ s,
                             const float* __restrict__ t,
                             const int* __restrict__ rowstart,
                             const int* __restrict__ bsum,
                             const int* __restrict__ degi,
                             const int* __restrict__ csr,
                             const float* __restrict__ bl1,
                             float* __restrict__ out) {
    int n = blockIdx.x * 256 + threadIdx.x;
    if (n >= N_NODES) return;
    int beg = rowstart[n] + bsum[n >> 8];
    int cnt = degi[n];
    float acc = 0.0f;
    int i = 0;
    for (; i + 4 <= cnt; i += 4) {
        int e0 = csr[beg + i], e1 = csr[beg + i + 1];
        int e2 = csr[beg + i + 2], e3 = csr[beg + i + 3];
        acc += s[e0] + s[e1] + s[e2] + s[e3];
    }
    for (; i < cnt; ++i) acc += s[csr[beg + i]];
    float v = acc / fmaxf((float)cnt, 1.0f) + bl1[0] + t[n];
    float sg = 1.0f / (1.0f + expf(-v));
    out[n] = v;
    out[N_NODES + n] = sg;
}

extern "C" void kernel_launch(void* const* d_in, const int* in_sizes, int n_in,
                              void* d_out, int out_size, void* d_ws, size_t ws_size,
                              hipStream_t stream) {
    const float* x   = (const float*)d_in[0];
    const int*   ei  = (const int*)d_in[1];   // int32, [2,E] flat: src row, dst row
    const float* Wl0 = (const float*)d_in[2];
    const float* bl0 = (const float*)d_in[3];
    const float* Wr0 = (const float*)d_in[4];
    const float* Wl1 = (const float*)d_in[5];
    const float* bl1 = (const float*)d_in[6];
    const float* Wr1 = (const float*)d_in[7];
    float* out = (float*)d_out;

    // Workspace layout (~25.6 MB, all offsets 16-B aligned):
    //   degi     @0            (400,000)    written by scan1 (totals)
    //   rowstart @400,000      (400,000)
    //   bsum     @800,000      (4,096)
    //   s        @804,096      (400,000)
    //   t        @1,204,096    (400,000)
    //   csr      @1,604,096    (4,000,000)
    //   pos      @5,604,096    (4,000,000)
    //   xb       @9,604,096    (12,800,000)  bf16 x rows
    //   wt       @22,404,096   (16,384)      bf16 [Wl0|Wr0] rows
    //   degi8    @22,420,480   (3,200,000)   8 XCD-private histograms, zeroed
    char* ws = (char*)d_ws;
    int*   degi     = (int*)(ws);
    int*   rowstart = (int*)(ws + 400000);
    int*   bsum     = (int*)(ws + 800000);
    float* s        = (float*)(ws + 804096);
    float* t        = (float*)(ws + 1204096);
    int*   csr      = (int*)(ws + 1604096);
    int*   pos      = (int*)(ws + 5604096);
    char*  xb       = (ws + 9604096);
    short* wt       = (short*)(ws + 22404096);
    int*   degi8    = (int*)(ws + 22420480);

    (void)hipMemsetAsync(degi8, 0, NCOPY * N_NODES * sizeof(int), stream);

    hist_convert_kernel<<<7228, 256, 0, stream>>>(ei, degi8, pos,
                                                  (const float4*)x, (uint2*)xb,
                                                  Wl0, Wr0, wt);
    scan1_kernel<<<SCAN_BLOCKS, 256, 0, stream>>>(degi8, degi, rowstart, bsum);
    scan2_kernel<<<1, 512, 0, stream>>>(bsum);
    fill_kernel<<<977, 256, 0, stream>>>(ei, rowstart, bsum, degi8, pos, csr);
    agg_gemm_kernel<<<6250, 256, 0, stream>>>((const uint2*)xb, (const short*)xb,
                                              wt, rowstart, bsum, degi, csr,
                                              bl0, Wl1, Wr1, s, t);
    final_kernel<<<SCAN_BLOCKS, 256, 0, stream>>>(s, t, rowstart, bsum, degi, csr,
                                                  bl1, out);
}